// Round 7
// baseline (6260.221 us; speedup 1.0000x reference)
//
#include <hip/hip_runtime.h>

#define BB 64
#define TT 4096
#define IN0 32
#define HH 128
#define G3 384
#define NOUT 32

typedef _Float16 h2 __attribute__((ext_vector_type(2)));
typedef _Float16 h8 __attribute__((ext_vector_type(8)));
union H8 { h8 v; h2 p[4]; };

// Per-WG LDS (~6 KB). Row sums are final (no K-split partials).
struct SM {
    float g[2 * HH];       // r,z pre-activations: gi+gh+both biases
    float gin[HH];         // n: input side (incl b_ih)
    float ghn[HH];         // n: hidden side (incl b_hh)
    float hs[2][HH];       // fp32 h (role C only, for fc)
    _Float16 hf[2][HH];    // f16 h for the dot2 matvec
    float pfc[2][NOUT * 9];
};

__device__ __forceinline__ float fast_sigmoid(float x) {
    x = fminf(fmaxf(x, -30.f), 30.f);
    float e = __expf(-x);
    return __builtin_amdgcn_rcpf(1.f + e);
}
__device__ __forceinline__ float fast_tanh(float x) {
    x = fminf(fmaxf(x, -15.f), 15.f);
    float e = __expf(-2.f * x);
    return (1.f - e) * __builtin_amdgcn_rcpf(1.f + e);
}
__device__ __forceinline__ float fdot2(h2 a, h2 b, float c) {
#if __has_builtin(__builtin_amdgcn_fdot2)
    return __builtin_amdgcn_fdot2(a, b, c, false);   // v_dot2_f32_f16, fp32 accum
#else
    return fmaf((float)a.x, (float)b.x, fmaf((float)a.y, (float)b.y, c));
#endif
}
__device__ __forceinline__ int aload(const int* p) {
    return __hip_atomic_load(p, __ATOMIC_RELAXED, __HIP_MEMORY_SCOPE_AGENT);
}
__device__ __forceinline__ void astore(int* p, int v) {
    __hip_atomic_store(p, v, __ATOMIC_RELAXED, __HIP_MEMORY_SCOPE_AGENT);
}
__device__ __forceinline__ h2 cvt2(float a, float b) {
    h2 r; r.x = (_Float16)a; r.y = (_Float16)b; return r;
}

// ---------------- Role A: layer-0 recurrence -> y0 (f16) ----------------
__device__ void role_A(SM& sm, const float* __restrict__ xb,
                       const float* __restrict__ W_ih, const float* __restrict__ W_hh,
                       const float* __restrict__ b_ih, const float* __restrict__ b_hh,
                       _Float16* __restrict__ y0b, float* __restrict__ hout, int* flagA)
{
    const int tid = threadIdx.x;          // = gate row r (full K)
    h2 wh[64], wi[16];
    #pragma unroll
    for (int k = 0; k < 64; ++k) {
        float2 f = *(const float2*)&W_hh[tid * HH + 2 * k];
        wh[k] = cvt2(f.x, f.y);
    }
    #pragma unroll
    for (int k = 0; k < 16; ++k) {
        float2 f = *(const float2*)&W_ih[tid * IN0 + 2 * k];
        wi[k] = cvt2(f.x, f.y);
    }
    const bool is_n = tid >= 2 * HH;      // wave-uniform (waves 4-5)
    const float bi = b_ih[tid], bh = b_hh[tid];
    float hreg = 0.f;
    if (tid < HH) sm.hf[0][tid] = (_Float16)0.f;

    // x[0] into regs (uniform-address loads), convert to f16
    float4 pf[8];
    #pragma unroll
    for (int i = 0; i < 8; ++i) pf[i] = ((const float4*)xb)[i];
    h2 xc[16];
    #pragma unroll
    for (int i = 0; i < 8; ++i) {
        xc[2 * i]     = cvt2(pf[i].x, pf[i].y);
        xc[2 * i + 1] = cvt2(pf[i].z, pf[i].w);
    }
    __syncthreads();

    int cur = 0;
    for (int t = 0; t < TT; ++t) {
        // prefetch x[t+1] (uniform address -> one coalesced request)
        const int tn = (t + 1 < TT) ? t + 1 : t;
        #pragma unroll
        for (int i = 0; i < 8; ++i) pf[i] = ((const float4*)(xb + (size_t)tn * IN0))[i];

        // full-K dots (16 h8 chunks = 128 K), 2 accumulators each
        float ah0 = bh, ah1 = 0.f;
        const h8* hv = (const h8*)&sm.hf[cur][0];
        #pragma unroll
        for (int i = 0; i < 16; ++i) {
            H8 hh; hh.v = hv[i];
            #pragma unroll
            for (int j = 0; j < 4; ++j) {
                if (((4 * i + j) & 1) == 0) ah0 = fdot2(wh[4 * i + j], hh.p[j], ah0);
                else                        ah1 = fdot2(wh[4 * i + j], hh.p[j], ah1);
            }
        }
        float ai0 = bi, ai1 = 0.f;
        #pragma unroll
        for (int j = 0; j < 16; ++j) {
            if (j & 1) ai1 = fdot2(wi[j], xc[j], ai1);
            else       ai0 = fdot2(wi[j], xc[j], ai0);
        }
        const float sgh = ah0 + ah1, sgi = ai0 + ai1;
        if (!is_n) sm.g[tid] = sgh + sgi;                       // r,z: combined
        else { sm.gin[tid - 2 * HH] = sgi; sm.ghn[tid - 2 * HH] = sgh; }
        __syncthreads();

        // gates (waves 0-1) / x convert (all)
        if (tid < HH) {
            float rg = fast_sigmoid(sm.g[tid]);
            float zg = fast_sigmoid(sm.g[tid + HH]);
            float ng = fast_tanh(sm.gin[tid] + rg * sm.ghn[tid]);
            hreg = (1.f - zg) * ng + zg * hreg;                 // h stays in a register
            sm.hf[cur ^ 1][tid] = (_Float16)hreg;
            y0b[(size_t)t * HH + tid] = (_Float16)hreg;
            if (t == TT - 1) hout[tid] = hreg;
        }
        #pragma unroll
        for (int i = 0; i < 8; ++i) {
            xc[2 * i]     = cvt2(pf[i].x, pf[i].y);
            xc[2 * i + 1] = cvt2(pf[i].z, pf[i].w);
        }
        __syncthreads();
        if ((t & 7) == 7 && tid == 0) { __threadfence(); astore(flagA, t + 1); }
        cur ^= 1;
    }
}

// ---------------- Role C: layer-1 recurrence + fused fc -> out ----------------
__device__ void role_C(SM& sm, const _Float16* __restrict__ yb,
                       const float* __restrict__ W_ih, const float* __restrict__ W_hh,
                       const float* __restrict__ b_ih, const float* __restrict__ b_hh,
                       const float* __restrict__ fc_w, const float* __restrict__ fc_b,
                       float* __restrict__ outb, float* __restrict__ hout, int* flagA)
{
    const int tid = threadIdx.x;
    h2 wh[64], wi[64];
    #pragma unroll
    for (int k = 0; k < 64; ++k) {
        float2 f = *(const float2*)&W_hh[tid * HH + 2 * k]; wh[k] = cvt2(f.x, f.y);
        float2 g = *(const float2*)&W_ih[tid * HH + 2 * k]; wi[k] = cvt2(g.x, g.y);
    }
    const bool is_n = tid >= 2 * HH;
    const float bi = b_ih[tid], bh = b_hh[tid];
    float hreg = 0.f;
    // fc weights in registers (threads 128..383: o = fidx&31, ks = fidx>>5)
    const int fidx = tid - HH, fo = fidx & 31, fks = fidx >> 5;
    float fw[16]; float fb = 0.f;
    if (tid >= HH) {
        #pragma unroll
        for (int i = 0; i < 16; ++i) fw[i] = fc_w[fo * HH + fks * 16 + i];
        if (tid < HH + NOUT) fb = fc_b[fo];
    }
    if (tid < HH) { sm.hf[0][tid] = (_Float16)0.f; sm.hs[0][tid] = 0.f; sm.hs[1][tid] = 0.f; }

    if (tid == 0) {   // initial lead: 16 steps
        while (aload(flagA) < 16) __builtin_amdgcn_s_sleep(8);
        __threadfence();
    }
    __syncthreads();
    H8 yv[16];
    #pragma unroll
    for (int i = 0; i < 16; ++i) yv[i].v = ((const h8*)yb)[i];

    int cur = 0;
    for (int t = 0; t < TT; ++t) {
        if (t && (t & 7) == 0) {          // stay ~16 steps behind A (covers prefetch t+8)
            if (tid == 0) {
                int tgt = t + 16; if (tgt > TT) tgt = TT;
                while (aload(flagA) < tgt) __builtin_amdgcn_s_sleep(2);
                __threadfence();
            }
            __syncthreads();
        }

        // full-K dots: gh from LDS hf (16 h8 chunks = 128 K), gi from yv registers
        float ah0 = bh, ah1 = 0.f;
        const h8* hv = (const h8*)&sm.hf[cur][0];
        #pragma unroll
        for (int i = 0; i < 16; ++i) {
            H8 hh; hh.v = hv[i];
            #pragma unroll
            for (int j = 0; j < 4; ++j) {
                if (((4 * i + j) & 1) == 0) ah0 = fdot2(wh[4 * i + j], hh.p[j], ah0);
                else                        ah1 = fdot2(wh[4 * i + j], hh.p[j], ah1);
            }
        }
        float ai0 = bi, ai1 = 0.f;
        #pragma unroll
        for (int i = 0; i < 16; ++i) {
            #pragma unroll
            for (int j = 0; j < 4; ++j) {
                if (((4 * i + j) & 1) == 0) ai0 = fdot2(wi[4 * i + j], yv[i].p[j], ai0);
                else                        ai1 = fdot2(wi[4 * i + j], yv[i].p[j], ai1);
            }
        }
        // prefetch y[t+1] into the same regs (after last read above)
        const int tn = (t + 1 < TT) ? t + 1 : t;
        const h8* ysrc = (const h8*)(yb + (size_t)tn * HH);
        #pragma unroll
        for (int i = 0; i < 16; ++i) yv[i].v = ysrc[i];

        const float sgh = ah0 + ah1, sgi = ai0 + ai1;
        if (!is_n) sm.g[tid] = sgh + sgi;
        else { sm.gin[tid - 2 * HH] = sgi; sm.ghn[tid - 2 * HH] = sgh; }

        // fc partial for y1[t-1] = hs[cur] (threads 128..383)
        if (tid >= HH) {
            const float* hvv = &sm.hs[cur][fks * 16];
            float s = 0.f;
            #pragma unroll
            for (int i = 0; i < 16; ++i) s = fmaf(fw[i], hvv[i], s);
            sm.pfc[t & 1][fo * 9 + fks] = s;
        }
        // fc reduce for y1[t-2] (threads 128..159)
        if (t >= 2 && tid >= HH && tid < HH + NOUT) {
            float s = fb;
            #pragma unroll
            for (int j = 0; j < 8; ++j) s += sm.pfc[(t - 1) & 1][fo * 9 + j];
            outb[(size_t)(t - 2) * NOUT + fo] = s;
        }
        __syncthreads();

        if (tid < HH) {
            float rg = fast_sigmoid(sm.g[tid]);
            float zg = fast_sigmoid(sm.g[tid + HH]);
            float ng = fast_tanh(sm.gin[tid] + rg * sm.ghn[tid]);
            hreg = (1.f - zg) * ng + zg * hreg;
            sm.hf[cur ^ 1][tid] = (_Float16)hreg;
            sm.hs[cur ^ 1][tid] = hreg;
            if (t == TT - 1) hout[tid] = hreg;
        }
        __syncthreads();
        cur ^= 1;
    }

    // epilogue: out[TT-2], then partial+reduce for y1[TT-1] = hs[cur]
    if (tid >= HH && tid < HH + NOUT) {
        float s = fb;
        #pragma unroll
        for (int j = 0; j < 8; ++j) s += sm.pfc[(TT - 1) & 1][fo * 9 + j];
        outb[(size_t)(TT - 2) * NOUT + fo] = s;
    }
    if (tid >= HH) {
        const float* hvv = &sm.hs[cur][fks * 16];
        float s = 0.f;
        #pragma unroll
        for (int i = 0; i < 16; ++i) s = fmaf(fw[i], hvv[i], s);
        sm.pfc[TT & 1][fo * 9 + fks] = s;
    }
    __syncthreads();
    if (tid >= HH && tid < HH + NOUT) {
        float s = fb;
        #pragma unroll
        for (int j = 0; j < 8; ++j) s += sm.pfc[TT & 1][fo * 9 + j];
        outb[(size_t)(TT - 1) * NOUT + fo] = s;
    }
}

// 384 thr = 6 waves; min 1 wave/EU -> VGPR cap large enough for ~230 regs in role C.
extern "C" __global__ void __launch_bounds__(384, 1)
__attribute__((amdgpu_waves_per_eu(1, 2)))
gru2_kernel(
    const float* x,
    const float* W_ih0, const float* W_hh0, const float* b_ih0, const float* b_hh0,
    const float* W_ih1, const float* W_hh1, const float* b_ih1, const float* b_hh1,
    const float* fc_w, const float* fc_b,
    float* out, float* hstack, _Float16* y0, int* flags)
{
    __shared__ SM sm;
    const int wg = blockIdx.x;
    if (wg < BB) {
        const int b = wg;
        role_A(sm, x + (size_t)b * TT * IN0, W_ih0, W_hh0, b_ih0, b_hh0,
               y0 + (size_t)b * TT * HH, hstack + b * HH, flags + b * 16);
    } else {
        const int b = wg - BB;   // b and b+64 map to the same XCD (64 % 8 == 0)
        role_C(sm, y0 + (size_t)b * TT * HH, W_ih1, W_hh1, b_ih1, b_hh1,
               fc_w, fc_b, out + (size_t)b * TT * NOUT,
               hstack + BB * HH + b * HH, flags + b * 16);
    }
}

extern "C" void kernel_launch(void* const* d_in, const int* in_sizes, int n_in,
                              void* d_out, int out_size, void* d_ws, size_t ws_size,
                              hipStream_t stream) {
    const float* x     = (const float*)d_in[0];
    const float* W_ih0 = (const float*)d_in[1];
    const float* W_hh0 = (const float*)d_in[2];
    const float* b_ih0 = (const float*)d_in[3];
    const float* b_hh0 = (const float*)d_in[4];
    const float* W_ih1 = (const float*)d_in[5];
    const float* W_hh1 = (const float*)d_in[6];
    const float* b_ih1 = (const float*)d_in[7];
    const float* b_hh1 = (const float*)d_in[8];
    const float* fc_w  = (const float*)d_in[9];
    const float* fc_b  = (const float*)d_in[10];

    float* out    = (float*)d_out;                        // [B,T,32]
    float* hstack = out + (size_t)BB * TT * NOUT;         // [2,B,128]
    _Float16* y0  = (_Float16*)d_ws;                      // [B,T,128] f16 (64 MB)
    int* flags    = (int*)((char*)d_ws + (80ull << 20));  // 64 flags, 64-B stride;
                                                          // 0xAA poison = negative -> waiters block

    gru2_kernel<<<2 * BB, 384, 0, stream>>>(
        x, W_ih0, W_hh0, b_ih0, b_hh0,
        W_ih1, W_hh1, b_ih1, b_hh1,
        fc_w, fc_b, out, hstack, y0, flags);
}